// Round 3
// baseline (282.385 us; speedup 1.0000x reference)
//
#include <hip/hip_runtime.h>

#define NBLOCKS 8192
#define NTHREADS 256
#define GROUPS 4
// 8192 blocks * 256 threads = 2^21 threads * 4 float4 groups = 2^25 elements.
// R5 structure: streaming loads, partials to d_ws, separate tiny final
// kernel. NO single-address atomics (R7/R8: 7-55 ns each, 8192 serialized
// = 60-450 us tail).
// R9 (third submit; two infra failures, source unchanged): NT loads ->
// plain cached loads (test whether the NT bypass path caps read BW below
// the 6.3-6.9 TB/s cached ceiling), and streaming loads hoisted ABOVE the
// weights/LDS/__syncthreads barrier so the 8 VMEM ops issue at wave start.

typedef float fvec4 __attribute__((ext_vector_type(4)));
typedef int   ivec4 __attribute__((ext_vector_type(4)));
typedef double dvec2 __attribute__((ext_vector_type(2)));

__global__ __launch_bounds__(NTHREADS) void wmse_kernel(
    const fvec4* __restrict__ pred4,
    const ivec4* __restrict__ lab4,
    const float* __restrict__ weights,
    double* __restrict__ partials,
    int n4)
{
    __shared__ float w[16];

    const int stride = NBLOCKS * NTHREADS;       // 2^21 float4 groups
    const int t = blockIdx.x * NTHREADS + threadIdx.x;

    double acc = 0.0;

    if (n4 == stride * GROUPS) {
        // ---- flat fast path: plain cached streaming loads, issued
        // BEFORE the weights staging + barrier ----
        fvec4 p0 = pred4[t];
        fvec4 p1 = pred4[t + stride];
        fvec4 p2 = pred4[t + 2 * stride];
        fvec4 p3 = pred4[t + 3 * stride];
        ivec4 l0 = lab4[t];
        ivec4 l1 = lab4[t + stride];
        ivec4 l2 = lab4[t + 2 * stride];
        ivec4 l3 = lab4[t + 3 * stride];

        if (threadIdx.x < 10) w[threadIdx.x] = weights[threadIdx.x];
        __syncthreads();

        float s0, s1, s2, s3;
        {
            float d0 = p0.x - (float)l0.x, d1 = p0.y - (float)l0.y;
            float d2 = p0.z - (float)l0.z, d3 = p0.w - (float)l0.w;
            s0 = w[l0.x]*d0*d0 + w[l0.y]*d1*d1 + w[l0.z]*d2*d2 + w[l0.w]*d3*d3;
        }
        {
            float d0 = p1.x - (float)l1.x, d1 = p1.y - (float)l1.y;
            float d2 = p1.z - (float)l1.z, d3 = p1.w - (float)l1.w;
            s1 = w[l1.x]*d0*d0 + w[l1.y]*d1*d1 + w[l1.z]*d2*d2 + w[l1.w]*d3*d3;
        }
        {
            float d0 = p2.x - (float)l2.x, d1 = p2.y - (float)l2.y;
            float d2 = p2.z - (float)l2.z, d3 = p2.w - (float)l2.w;
            s2 = w[l2.x]*d0*d0 + w[l2.y]*d1*d1 + w[l2.z]*d2*d2 + w[l2.w]*d3*d3;
        }
        {
            float d0 = p3.x - (float)l3.x, d1 = p3.y - (float)l3.y;
            float d2 = p3.z - (float)l3.z, d3 = p3.w - (float)l3.w;
            s3 = w[l3.x]*d0*d0 + w[l3.y]*d1*d1 + w[l3.z]*d2*d2 + w[l3.w]*d3*d3;
        }
        acc = (double)((s0 + s1) + (s2 + s3));
    } else {
        // generic fallback (not taken for N = 2^25)
        if (threadIdx.x < 10) w[threadIdx.x] = weights[threadIdx.x];
        __syncthreads();
        for (int i = t; i < n4; i += stride) {
            fvec4 p = pred4[i];
            ivec4 l = lab4[i];
            float d0 = p.x - (float)l.x, d1 = p.y - (float)l.y;
            float d2 = p.z - (float)l.z, d3 = p.w - (float)l.w;
            acc += (double)(w[l.x]*d0*d0 + w[l.y]*d1*d1
                          + w[l.z]*d2*d2 + w[l.w]*d3*d3);
        }
    }

    // 64-lane wave shuffle reduction (f64)
    for (int off = 32; off > 0; off >>= 1)
        acc += __shfl_down(acc, off, 64);

    __shared__ double wave_sums[NTHREADS / 64];
    int lane = threadIdx.x & 63;
    int wid  = threadIdx.x >> 6;
    if (lane == 0) wave_sums[wid] = acc;
    __syncthreads();

    if (threadIdx.x == 0) {
        double tsum = 0.0;
        #pragma unroll
        for (int k = 0; k < NTHREADS / 64; ++k) tsum += wave_sums[k];
        partials[blockIdx.x] = tsum;
    }
}

#define FTHREADS 1024

__global__ __launch_bounds__(FTHREADS) void wmse_final_kernel(
    const dvec2* __restrict__ partials2,   // NBLOCKS/2 double2s
    float* __restrict__ out,
    double inv_n)
{
    // NBLOCKS/2 = 4096 double2; 1024 threads -> 4 vector loads each
    double acc = 0.0;
    #pragma unroll
    for (int k = 0; k < NBLOCKS / 2 / FTHREADS; ++k) {
        dvec2 v = partials2[threadIdx.x + k * FTHREADS];
        acc += v.x + v.y;
    }

    for (int off = 32; off > 0; off >>= 1)
        acc += __shfl_down(acc, off, 64);

    __shared__ double wave_sums[FTHREADS / 64];
    int lane = threadIdx.x & 63;
    int wid  = threadIdx.x >> 6;
    if (lane == 0) wave_sums[wid] = acc;
    __syncthreads();

    if (threadIdx.x == 0) {
        double t = 0.0;
        #pragma unroll
        for (int k = 0; k < FTHREADS / 64; ++k) t += wave_sums[k];
        out[0] = (float)(t * inv_n);
    }
}

extern "C" void kernel_launch(void* const* d_in, const int* in_sizes, int n_in,
                              void* d_out, int out_size, void* d_ws, size_t ws_size,
                              hipStream_t stream) {
    const float* pred    = (const float*)d_in[0];
    const int*   labels  = (const int*)d_in[1];
    const float* weights = (const float*)d_in[2];
    float* out = (float*)d_out;

    int n  = in_sizes[0];          // 33,554,432 = 2^25
    int n4 = n >> 2;

    double* partials = (double*)d_ws;   // 8192 doubles = 64 KB

    wmse_kernel<<<NBLOCKS, NTHREADS, 0, stream>>>(
        (const fvec4*)pred, (const ivec4*)labels, weights, partials, n4);

    wmse_final_kernel<<<1, FTHREADS, 0, stream>>>(
        (const dvec2*)partials, out, 1.0 / (double)n);
}

// Round 4
// 254.374 us; speedup vs baseline: 1.1101x; 1.1101x over previous
//
#include <hip/hip_runtime.h>

#define NBLOCKS 2048
#define NTHREADS 256
#define ITERS 16
// R10: restore NT loads (R9 proved cached loads regress: 72us -> 101us
// kernel; dirty-L3 eviction writebacks from the harness poison fills) and
// replace the one-shot 8192-block structure with a single-occupancy-round
// persistent grid: 2048 blocks (8/CU = 32 waves/CU in ONE launch round),
// each thread loops 16 float4 groups, unroll-4 so ~8 NT loads stay in
// flight continuously (fill-kernel-like streaming; amortizes per-block
// prologue that the 4-round one-shot paid 4x).
// Structure otherwise R5-proven: partials to d_ws, tiny final kernel,
// NO single-address atomics.

typedef float fvec4 __attribute__((ext_vector_type(4)));
typedef int   ivec4 __attribute__((ext_vector_type(4)));
typedef double dvec2 __attribute__((ext_vector_type(2)));

__device__ __forceinline__ fvec4 ntloadf(const fvec4* p) {
    return __builtin_nontemporal_load(p);
}
__device__ __forceinline__ ivec4 ntloadi(const ivec4* p) {
    return __builtin_nontemporal_load(p);
}

__global__ __launch_bounds__(NTHREADS) void wmse_kernel(
    const fvec4* __restrict__ pred4,
    const ivec4* __restrict__ lab4,
    const float* __restrict__ weights,
    double* __restrict__ partials,
    int n4)
{
    __shared__ float w[16];
    if (threadIdx.x < 10) w[threadIdx.x] = weights[threadIdx.x];
    __syncthreads();

    const int S = NBLOCKS * NTHREADS;            // 2^19 threads
    const int t = blockIdx.x * NTHREADS + threadIdx.x;

    double acc = 0.0;

    if (n4 == S * ITERS) {
        // ---- flat fast path: continuous NT streaming, 16 groups/thread ----
        #pragma unroll 4
        for (int k = 0; k < ITERS; ++k) {
            const int idx = t + k * S;
            fvec4 p = ntloadf(pred4 + idx);
            ivec4 l = ntloadi(lab4 + idx);
            float d0 = p.x - (float)l.x, d1 = p.y - (float)l.y;
            float d2 = p.z - (float)l.z, d3 = p.w - (float)l.w;
            float s = w[l.x]*d0*d0 + w[l.y]*d1*d1
                    + w[l.z]*d2*d2 + w[l.w]*d3*d3;
            acc += (double)s;
        }
    } else {
        // generic fallback (not taken for N = 2^25)
        for (int i = t; i < n4; i += S) {
            fvec4 p = pred4[i];
            ivec4 l = lab4[i];
            float d0 = p.x - (float)l.x, d1 = p.y - (float)l.y;
            float d2 = p.z - (float)l.z, d3 = p.w - (float)l.w;
            acc += (double)(w[l.x]*d0*d0 + w[l.y]*d1*d1
                          + w[l.z]*d2*d2 + w[l.w]*d3*d3);
        }
    }

    // 64-lane wave shuffle reduction (f64)
    for (int off = 32; off > 0; off >>= 1)
        acc += __shfl_down(acc, off, 64);

    __shared__ double wave_sums[NTHREADS / 64];
    int lane = threadIdx.x & 63;
    int wid  = threadIdx.x >> 6;
    if (lane == 0) wave_sums[wid] = acc;
    __syncthreads();

    if (threadIdx.x == 0) {
        double tsum = 0.0;
        #pragma unroll
        for (int k = 0; k < NTHREADS / 64; ++k) tsum += wave_sums[k];
        partials[blockIdx.x] = tsum;
    }
}

#define FTHREADS 1024

__global__ __launch_bounds__(FTHREADS) void wmse_final_kernel(
    const dvec2* __restrict__ partials2,   // NBLOCKS/2 double2s
    float* __restrict__ out,
    double inv_n)
{
    // NBLOCKS/2 = 1024 double2; 1024 threads -> 1 vector load each
    double acc = 0.0;
    #pragma unroll
    for (int k = 0; k < NBLOCKS / 2 / FTHREADS; ++k) {
        dvec2 v = partials2[threadIdx.x + k * FTHREADS];
        acc += v.x + v.y;
    }

    for (int off = 32; off > 0; off >>= 1)
        acc += __shfl_down(acc, off, 64);

    __shared__ double wave_sums[FTHREADS / 64];
    int lane = threadIdx.x & 63;
    int wid  = threadIdx.x >> 6;
    if (lane == 0) wave_sums[wid] = acc;
    __syncthreads();

    if (threadIdx.x == 0) {
        double t = 0.0;
        #pragma unroll
        for (int k = 0; k < FTHREADS / 64; ++k) t += wave_sums[k];
        out[0] = (float)(t * inv_n);
    }
}

extern "C" void kernel_launch(void* const* d_in, const int* in_sizes, int n_in,
                              void* d_out, int out_size, void* d_ws, size_t ws_size,
                              hipStream_t stream) {
    const float* pred    = (const float*)d_in[0];
    const int*   labels  = (const int*)d_in[1];
    const float* weights = (const float*)d_in[2];
    float* out = (float*)d_out;

    int n  = in_sizes[0];          // 33,554,432 = 2^25
    int n4 = n >> 2;

    double* partials = (double*)d_ws;   // 2048 doubles = 16 KB

    wmse_kernel<<<NBLOCKS, NTHREADS, 0, stream>>>(
        (const fvec4*)pred, (const ivec4*)labels, weights, partials, n4);

    wmse_final_kernel<<<1, FTHREADS, 0, stream>>>(
        (const dvec2*)partials, out, 1.0 / (double)n);
}